// Round 1
// 3128.258 us; speedup vs baseline: 3.3422x; 3.3422x over previous
//
#include <hip/hip_runtime.h>
#include <math.h>

// NeighborAttentionV2 — Round 2: split-precision bf16 MFMA edge kernel.
// Every GEMM operand is decomposed x = hi + lo (bf16 RNE pair); each tile does
// Ah*Bh + Al*Bh + Ah*Bl via v_mfma_f32_16x16x32_bf16 with fp32 accumulation
// (dropped Al*Bl term ~2^-18 relative -> fp32-class accuracy).
// MFMA floor: 3 * 315 GFLOP = 946 GFLOP @ ~2.1 PF ceiling = ~0.46 ms.
// Weights are pre-packed into exact B-fragment lane order (hi/lo) by pack_kernel
// into d_out used as scratch (node_kernel fully overwrites d_out afterwards).
// LDS: 69.3 KB/block (padded strides, 2-way bank alias = free) -> 2 blocks/CU.

#define NH 128      // num_hidden
#define NI 256      // num_in
#define HEADS 4
#define TE 32       // edges per block (2 MFMA M-tiles)
#define TN 16       // nodes per block (kernel 2)
#define SH (NH + 4) // node kernel LDS stride

typedef unsigned short u16;
typedef unsigned int u32;
typedef __attribute__((ext_vector_type(8))) short short8v;  // 8 bf16 = 4 VGPR
typedef __attribute__((ext_vector_type(4))) float f32x4;

__device__ __forceinline__ u16 f2bf(float x) {
    u32 u = __float_as_uint(x);
    return (u16)((u + 0x7FFFu + ((u >> 16) & 1u)) >> 16);   // RNE
}
__device__ __forceinline__ float bf2f(u16 h) { return __uint_as_float((u32)h << 16); }
__device__ __forceinline__ float gelu_f(float x) {
    return 0.5f * x * (1.0f + erff(x * 0.70710678118654752f));
}

// Pack W[N][K] (f32 row-major) into MFMA B-fragment order, hi/lo bf16.
// Fragment: lane l holds B[k][n] with n = nt*16 + (l&15), k = ks*32 + (l>>4)*8 + j.
__global__ void pack_kernel(const float* __restrict__ W, int N, int K,
                            u16* __restrict__ ph, u16* __restrict__ pl) {
    int idx = blockIdx.x * 256 + threadIdx.x;
    if (idx >= N * K) return;
    int KS = K >> 5;
    int j = idx & 7, l = (idx >> 3) & 63, rest = idx >> 9;
    int ks = rest % KS, nt = rest / KS;
    int n = nt * 16 + (l & 15);
    int k = ks * 32 + ((l >> 4) << 3) + j;
    float w0 = W[(size_t)n * K + k];
    u16 h = f2bf(w0);
    ph[idx] = h;
    pl[idx] = f2bf(w0 - bf2f(h));
}

#define BFRAG(P, nt, KS, ks) (*(const short8v*)&(P)[(((size_t)(nt) * (KS) + (ks)) * 64 + l) * 8])
#define MFMA3(ACC, AH, AL, BH, BL)                                                \
    {                                                                             \
        ACC = __builtin_amdgcn_mfma_f32_16x16x32_bf16(AH, BH, ACC, 0, 0, 0);      \
        ACC = __builtin_amdgcn_mfma_f32_16x16x32_bf16(AL, BH, ACC, 0, 0, 0);      \
        ACC = __builtin_amdgcn_mfma_f32_16x16x32_bf16(AH, BL, ACC, 0, 0, 0);      \
    }

__global__ __launch_bounds__(256, 2) void edge_kernel(
    const float* __restrict__ hV, const float* __restrict__ hE,
    const int* __restrict__ cid_g,
    const u16* __restrict__ pm1h, const u16* __restrict__ pm1l,
    const u16* __restrict__ pm2h, const u16* __restrict__ pm2l,
    const u16* __restrict__ pv1h, const u16* __restrict__ pv1l,
    const u16* __restrict__ pv2h, const u16* __restrict__ pv2l,
    const u16* __restrict__ pv3h, const u16* __restrict__ pv3l,
    const float* __restrict__ bv1, const float* __restrict__ bv2,
    const float* __restrict__ bv3,
    const float* __restrict__ bm1, const float* __restrict__ bm2,
    const float* __restrict__ Wm3, const float* __restrict__ bm3,
    float* __restrict__ num, float* __restrict__ den)
{
    // Region reuse: XE holds hE, later m1-out (a1, 256 cols).
    //               XV holds gathered hV, later v1-out (128 cols).
    //               B2 holds m2-out, later v2-out.
    // Strides +8 elems: row-to-row bank shift 4 -> 2-way alias (free), 16B aligned.
    __shared__ u16 XEh[TE][264], XEl[TE][264];
    __shared__ u16 XVh[TE][136], XVl[TE][136];
    __shared__ u16 B2h[TE][136], B2l[TE][136];
    __shared__ float lg_s[TE][HEADS];
    __shared__ int cid_s[TE];

    const int t = threadIdx.x;
    const int l = t & 63, w = t >> 6;
    const int arow = l & 15, acg = l >> 4;   // A/D lane decomposition
    const int e0 = blockIdx.x * TE;

    if (t < TE) cid_s[t] = cid_g[e0 + t];

    // ---- stage h_E (32x256 f32) -> XE hi/lo ----
    {
        const float4* src = (const float4*)(hE + (size_t)e0 * NI);
        #pragma unroll
        for (int i = 0; i < 8; ++i) {
            int idx = t + 256 * i; int e = idx >> 6, c4 = idx & 63;
            float4 v = src[(size_t)e * 64 + c4];
            u16 hx = f2bf(v.x), hy = f2bf(v.y), hz = f2bf(v.z), hw = f2bf(v.w);
            u32 h01 = (u32)hx | ((u32)hy << 16), h23 = (u32)hz | ((u32)hw << 16);
            u32 l01 = (u32)f2bf(v.x - bf2f(hx)) | ((u32)f2bf(v.y - bf2f(hy)) << 16);
            u32 l23 = (u32)f2bf(v.z - bf2f(hz)) | ((u32)f2bf(v.w - bf2f(hw)) << 16);
            *(uint2*)&XEh[e][c4 * 4] = make_uint2(h01, h23);
            *(uint2*)&XEl[e][c4 * 4] = make_uint2(l01, l23);
        }
    }
    // ---- gather h_V[center] (32x128 f32) -> XV hi/lo ----
    {
        #pragma unroll
        for (int i = 0; i < 4; ++i) {
            int idx = t + 256 * i; int e = idx >> 5, c4 = idx & 31;
            int row = cid_g[e0 + e];
            float4 v = ((const float4*)(hV + (size_t)row * NH))[c4];
            u16 hx = f2bf(v.x), hy = f2bf(v.y), hz = f2bf(v.z), hw = f2bf(v.w);
            u32 h01 = (u32)hx | ((u32)hy << 16), h23 = (u32)hz | ((u32)hw << 16);
            u32 l01 = (u32)f2bf(v.x - bf2f(hx)) | ((u32)f2bf(v.y - bf2f(hy)) << 16);
            u32 l23 = (u32)f2bf(v.z - bf2f(hz)) | ((u32)f2bf(v.w - bf2f(hw)) << 16);
            *(uint2*)&XVh[e][c4 * 4] = make_uint2(h01, h23);
            *(uint2*)&XVl[e][c4 * 4] = make_uint2(l01, l23);
        }
    }
    __syncthreads();   // B1: XE, XV, cid ready

    // ================= phase A: v1 (K=256) and m1 (K=384), acc in regs =======
    f32x4 vacc[2][2] = {};   // v1: wave owns n-tiles w*2..w*2+1   (cols w*32..)
    f32x4 macc[2][4] = {};   // m1: wave owns n-tiles w*4..w*4+3   (cols w*64..)

    #pragma unroll 2
    for (int ks = 0; ks < 8; ++ks) {          // v1 from XE
        short8v ah[2], al[2];
        #pragma unroll
        for (int mt = 0; mt < 2; ++mt) {
            ah[mt] = *(const short8v*)&XEh[mt * 16 + arow][ks * 32 + acg * 8];
            al[mt] = *(const short8v*)&XEl[mt * 16 + arow][ks * 32 + acg * 8];
        }
        #pragma unroll
        for (int ntl = 0; ntl < 2; ++ntl) {
            int nt = w * 2 + ntl;
            short8v bh = BFRAG(pv1h, nt, 8, ks);
            short8v bl = BFRAG(pv1l, nt, 8, ks);
            #pragma unroll
            for (int mt = 0; mt < 2; ++mt) MFMA3(vacc[mt][ntl], ah[mt], al[mt], bh, bl);
        }
    }
    #pragma unroll 2
    for (int ks = 0; ks < 4; ++ks) {          // m1 part A: k 0..127 from XV
        short8v ah[2], al[2];
        #pragma unroll
        for (int mt = 0; mt < 2; ++mt) {
            ah[mt] = *(const short8v*)&XVh[mt * 16 + arow][ks * 32 + acg * 8];
            al[mt] = *(const short8v*)&XVl[mt * 16 + arow][ks * 32 + acg * 8];
        }
        #pragma unroll
        for (int ntl = 0; ntl < 4; ++ntl) {
            int nt = w * 4 + ntl;
            short8v bh = BFRAG(pm1h, nt, 12, ks);
            short8v bl = BFRAG(pm1l, nt, 12, ks);
            #pragma unroll
            for (int mt = 0; mt < 2; ++mt) MFMA3(macc[mt][ntl], ah[mt], al[mt], bh, bl);
        }
    }
    #pragma unroll 2
    for (int ks = 4; ks < 12; ++ks) {         // m1 part B: k 128..383 from XE
        short8v ah[2], al[2];
        #pragma unroll
        for (int mt = 0; mt < 2; ++mt) {
            ah[mt] = *(const short8v*)&XEh[mt * 16 + arow][(ks - 4) * 32 + acg * 8];
            al[mt] = *(const short8v*)&XEl[mt * 16 + arow][(ks - 4) * 32 + acg * 8];
        }
        #pragma unroll
        for (int ntl = 0; ntl < 4; ++ntl) {
            int nt = w * 4 + ntl;
            short8v bh = BFRAG(pm1h, nt, 12, ks);
            short8v bl = BFRAG(pm1l, nt, 12, ks);
            #pragma unroll
            for (int mt = 0; mt < 2; ++mt) MFMA3(macc[mt][ntl], ah[mt], al[mt], bh, bl);
        }
    }
    __syncthreads();   // B2: all reads of XE/XV done -> regions reusable

    // epilogues: bias + gelu + hi/lo split. D layout: col=arow(+16*nt), row=acg*4+r.
    #pragma unroll
    for (int ntl = 0; ntl < 2; ++ntl) {       // v1-out -> XV region
        int n = (w * 2 + ntl) * 16 + arow;
        float b = bv1[n];
        #pragma unroll
        for (int mt = 0; mt < 2; ++mt)
            #pragma unroll
            for (int r = 0; r < 4; ++r) {
                int e = mt * 16 + acg * 4 + r;
                float g = gelu_f(vacc[mt][ntl][r] + b);
                u16 hh = f2bf(g);
                XVh[e][n] = hh; XVl[e][n] = f2bf(g - bf2f(hh));
            }
    }
    #pragma unroll
    for (int ntl = 0; ntl < 4; ++ntl) {       // m1-out (a1) -> XE region
        int n = (w * 4 + ntl) * 16 + arow;
        float b = bm1[n];
        #pragma unroll
        for (int mt = 0; mt < 2; ++mt)
            #pragma unroll
            for (int r = 0; r < 4; ++r) {
                int e = mt * 16 + acg * 4 + r;
                float g = gelu_f(macc[mt][ntl][r] + b);
                u16 hh = f2bf(g);
                XEh[e][n] = hh; XEl[e][n] = f2bf(g - bf2f(hh));
            }
    }
    __syncthreads();   // B3: a1 / v1-out ready

    // ================= m2: a1[32,256] @ Wm2^T -> B2 =========================
    {
        f32x4 acc2[2][2] = {};
        #pragma unroll 2
        for (int ks = 0; ks < 8; ++ks) {
            short8v ah[2], al[2];
            #pragma unroll
            for (int mt = 0; mt < 2; ++mt) {
                ah[mt] = *(const short8v*)&XEh[mt * 16 + arow][ks * 32 + acg * 8];
                al[mt] = *(const short8v*)&XEl[mt * 16 + arow][ks * 32 + acg * 8];
            }
            #pragma unroll
            for (int ntl = 0; ntl < 2; ++ntl) {
                int nt = w * 2 + ntl;
                short8v bh = BFRAG(pm2h, nt, 8, ks);
                short8v bl = BFRAG(pm2l, nt, 8, ks);
                #pragma unroll
                for (int mt = 0; mt < 2; ++mt) MFMA3(acc2[mt][ntl], ah[mt], al[mt], bh, bl);
            }
        }
        #pragma unroll
        for (int ntl = 0; ntl < 2; ++ntl) {
            int n = (w * 2 + ntl) * 16 + arow;
            float b = bm2[n];
            #pragma unroll
            for (int mt = 0; mt < 2; ++mt)
                #pragma unroll
                for (int r = 0; r < 4; ++r) {
                    int e = mt * 16 + acg * 4 + r;
                    float g = gelu_f(acc2[mt][ntl][r] + b);
                    u16 hh = f2bf(g);
                    B2h[e][n] = hh; B2l[e][n] = f2bf(g - bf2f(hh));
                }
        }
    }
    __syncthreads();   // B4: B2 (m2-out) ready

    // ================= m3 (N=4, VALU) + exp + den atomics ===================
    if (t < TE * HEADS) {
        int e = t >> 2, h = t & 3;
        float acc = bm3[h];
        for (int k8 = 0; k8 < 16; ++k8) {
            short8v hh = *(const short8v*)&B2h[e][k8 * 8];
            short8v ll = *(const short8v*)&B2l[e][k8 * 8];
            #pragma unroll
            for (int j = 0; j < 8; ++j)
                acc += (bf2f((u16)hh[j]) + bf2f((u16)ll[j])) * Wm3[h * NH + k8 * 8 + j];
        }
        float p = expf(acc * 0.17677669529663687f);   // / sqrt(32)
        lg_s[e][h] = p;
        atomicAdd(&den[(size_t)cid_s[e] * HEADS + h], p);
    }
    __syncthreads();   // B5: m3 done reading B2; lg ready

    // ================= v2: v1out[32,128] @ Wv2^T -> B2 (reuse) ==============
    {
        f32x4 acc3[2][2] = {};
        #pragma unroll 2
        for (int ks = 0; ks < 4; ++ks) {
            short8v ah[2], al[2];
            #pragma unroll
            for (int mt = 0; mt < 2; ++mt) {
                ah[mt] = *(const short8v*)&XVh[mt * 16 + arow][ks * 32 + acg * 8];
                al[mt] = *(const short8v*)&XVl[mt * 16 + arow][ks * 32 + acg * 8];
            }
            #pragma unroll
            for (int ntl = 0; ntl < 2; ++ntl) {
                int nt = w * 2 + ntl;
                short8v bh = BFRAG(pv2h, nt, 4, ks);
                short8v bl = BFRAG(pv2l, nt, 4, ks);
                #pragma unroll
                for (int mt = 0; mt < 2; ++mt) MFMA3(acc3[mt][ntl], ah[mt], al[mt], bh, bl);
            }
        }
        #pragma unroll
        for (int ntl = 0; ntl < 2; ++ntl) {
            int n = (w * 2 + ntl) * 16 + arow;
            float b = bv2[n];
            #pragma unroll
            for (int mt = 0; mt < 2; ++mt)
                #pragma unroll
                for (int r = 0; r < 4; ++r) {
                    int e = mt * 16 + acg * 4 + r;
                    float g = gelu_f(acc3[mt][ntl][r] + b);
                    u16 hh = f2bf(g);
                    B2h[e][n] = hh; B2l[e][n] = f2bf(g - bf2f(hh));
                }
        }
    }
    __syncthreads();   // B6: B2 (v2-out) ready

    // ================= v3 (no gelu) + weighted scatter ======================
    {
        f32x4 acc4[2][2] = {};
        #pragma unroll 2
        for (int ks = 0; ks < 4; ++ks) {
            short8v ah[2], al[2];
            #pragma unroll
            for (int mt = 0; mt < 2; ++mt) {
                ah[mt] = *(const short8v*)&B2h[mt * 16 + arow][ks * 32 + acg * 8];
                al[mt] = *(const short8v*)&B2l[mt * 16 + arow][ks * 32 + acg * 8];
            }
            #pragma unroll
            for (int ntl = 0; ntl < 2; ++ntl) {
                int nt = w * 2 + ntl;
                short8v bh = BFRAG(pv3h, nt, 4, ks);
                short8v bl = BFRAG(pv3l, nt, 4, ks);
                #pragma unroll
                for (int mt = 0; mt < 2; ++mt) MFMA3(acc4[mt][ntl], ah[mt], al[mt], bh, bl);
            }
        }
        #pragma unroll
        for (int ntl = 0; ntl < 2; ++ntl) {
            int n = (w * 2 + ntl) * 16 + arow;
            float b = bv3[n];
            int hd = n >> 5;
            #pragma unroll
            for (int mt = 0; mt < 2; ++mt)
                #pragma unroll
                for (int r = 0; r < 4; ++r) {
                    int e = mt * 16 + acg * 4 + r;
                    float val = (acc4[mt][ntl][r] + b) * lg_s[e][hd];
                    atomicAdd(&num[(size_t)cid_s[e] * NH + n], val);
                }
        }
    }
}

// out[n] = (num[n]/den[n,broadcast]) @ Wo^T  (unchanged, small)
__global__ __launch_bounds__(256) void node_kernel(
    const float* __restrict__ num, const float* __restrict__ den,
    const float* __restrict__ Wo, float* __restrict__ out)
{
    __shared__ float agg[TN][SH];
    const int t  = threadIdx.x;
    const int n0 = blockIdx.x * TN;

    #pragma unroll
    for (int i = 0; i < 2; ++i) {
        int idx = t + 256 * i;
        int nl = idx >> 5, c4 = idx & 31;
        int n = n0 + nl;
        float4 v = *(const float4*)&num[(size_t)n * NH + c4 * 4];
        float d = den[(size_t)n * HEADS + (c4 >> 3)];
        float r = (d != 0.0f) ? 1.0f / d : 0.0f;
        v.x *= r; v.y *= r; v.z *= r; v.w *= r;
        *(float4*)&agg[nl][c4 * 4] = v;
    }
    __syncthreads();

    const int ng = t & 7, jg = t >> 3;
    const int na = ng * 2, nb = na + 1;
    float acc[2][4] = {};
    for (int k = 0; k < NH; k += 4) {
        float4 xa = *(const float4*)&agg[na][k];
        float4 xb = *(const float4*)&agg[nb][k];
        #pragma unroll
        for (int jj = 0; jj < 4; ++jj) {
            const float4 wv = *(const float4*)&Wo[(size_t)(jg * 4 + jj) * 128 + k];
            acc[0][jj] += xa.x*wv.x + xa.y*wv.y + xa.z*wv.z + xa.w*wv.w;
            acc[1][jj] += xb.x*wv.x + xb.y*wv.y + xb.z*wv.z + xb.w*wv.w;
        }
    }
    #pragma unroll
    for (int jj = 0; jj < 4; ++jj) {
        out[(size_t)(n0 + na) * NH + jg * 4 + jj] = acc[0][jj];
        out[(size_t)(n0 + nb) * NH + jg * 4 + jj] = acc[1][jj];
    }
}

extern "C" void kernel_launch(void* const* d_in, const int* in_sizes, int n_in,
                              void* d_out, int out_size, void* d_ws, size_t ws_size,
                              hipStream_t stream) {
    const float* hV  = (const float*)d_in[0];
    const float* hE  = (const float*)d_in[1];
    const int*   cid = (const int*)  d_in[2];
    const float* Wv1 = (const float*)d_in[3];
    const float* bv1 = (const float*)d_in[4];
    const float* Wv2 = (const float*)d_in[5];
    const float* bv2 = (const float*)d_in[6];
    const float* Wv3 = (const float*)d_in[7];
    const float* bv3 = (const float*)d_in[8];
    const float* Wm1 = (const float*)d_in[9];
    const float* bm1 = (const float*)d_in[10];
    const float* Wm2 = (const float*)d_in[11];
    const float* bm2 = (const float*)d_in[12];
    const float* Wm3 = (const float*)d_in[13];
    const float* bm3 = (const float*)d_in[14];
    const float* Wo  = (const float*)d_in[15];

    const int N = in_sizes[0] / NH;   // 50000
    const int E = in_sizes[1] / NI;   // 800000 (divisible by TE=32)

    float* num = (float*)d_ws;                    // [N][128]
    float* den = num + (size_t)N * NH;            // [N][4]

    // packed weights live in d_out (scratch until node_kernel overwrites it)
    u16* pk = (u16*)d_out;
    u16 *pm1h = pk,           *pm1l = pk + 98304;   // Wm1: 256x384
    u16 *pm2h = pk + 196608,  *pm2l = pk + 229376;  // Wm2: 128x256
    u16 *pv1h = pk + 262144,  *pv1l = pk + 294912;  // Wv1: 128x256
    u16 *pv2h = pk + 327680,  *pv2l = pk + 344064;  // Wv2: 128x128
    u16 *pv3h = pk + 360448,  *pv3l = pk + 376832;  // Wv3: 128x128

    hipMemsetAsync(d_ws, 0, (size_t)N * (NH + HEADS) * sizeof(float), stream);
    pack_kernel<<<384, 256, 0, stream>>>(Wm1, 256, 384, pm1h, pm1l);
    pack_kernel<<<128, 256, 0, stream>>>(Wm2, 128, 256, pm2h, pm2l);
    pack_kernel<<<128, 256, 0, stream>>>(Wv1, 128, 256, pv1h, pv1l);
    pack_kernel<<< 64, 256, 0, stream>>>(Wv2, 128, 128, pv2h, pv2l);
    pack_kernel<<< 64, 256, 0, stream>>>(Wv3, 128, 128, pv3h, pv3l);
    edge_kernel<<<E / TE, 256, 0, stream>>>(hV, hE, cid,
        pm1h, pm1l, pm2h, pm2l, pv1h, pv1l, pv2h, pv2l, pv3h, pv3l,
        bv1, bv2, bv3, bm1, bm2, Wm3, bm3, num, den);
    node_kernel<<<N / TN, 256, 0, stream>>>(num, den, Wo, (float*)d_out);
}